// Round 1
// baseline (1026.990 us; speedup 1.0000x reference)
//
#include <hip/hip_runtime.h>
#include <hip/hip_bf16.h>
#include <math.h>

typedef __attribute__((ext_vector_type(4))) float f32x4;
typedef __attribute__((ext_vector_type(8))) short s16x8;

#define BB 4
#define TT 2048
#define CC 2048
#define NHEAD 16
#define KVH 4
#define HD 128
#define BT (BB*TT)      // 8192
#define NHC 2048        // N*H
#define KHC 512         // K*H
#define QKVC 3072

__device__ __forceinline__ float bf2f(unsigned short u) {
  union { unsigned u; float f; } v; v.u = ((unsigned)u) << 16; return v.f;
}
__device__ __forceinline__ unsigned short f2bf(float f) {
  union { float f; unsigned u; } v; v.f = f;
  unsigned r = v.u + 0x7fff + ((v.u >> 16) & 1);
  return (unsigned short)(r >> 16);
}

// ---------------- fp32 -> bf16 elementwise ----------------
__global__ void cvt_f2b(const float* __restrict__ in, unsigned short* __restrict__ out, int n4) {
  int i = blockIdx.x * 256 + threadIdx.x;
  if (i >= n4) return;
  float4 v = ((const float4*)in)[i];
  ushort4 o;
  o.x = f2bf(v.x); o.y = f2bf(v.y); o.z = f2bf(v.z); o.w = f2bf(v.w);
  ((ushort4*)out)[i] = o;
}

// ---------------- fp32 [R][Cc] -> bf16 [Cc][R] transpose ----------------
__global__ void trans_f2b(const float* __restrict__ in, unsigned short* __restrict__ out, int R, int Cc) {
  __shared__ float tile[32][33];
  int c0 = blockIdx.x * 32, r0 = blockIdx.y * 32;
  int tx = threadIdx.x, ty = threadIdx.y;
  #pragma unroll
  for (int k = 0; k < 4; k++)
    tile[ty + 8*k][tx] = in[(size_t)(r0 + ty + 8*k) * Cc + c0 + tx];
  __syncthreads();
  #pragma unroll
  for (int k = 0; k < 4; k++)
    out[(size_t)(c0 + ty + 8*k) * R + r0 + tx] = f2bf(tile[tx][ty + 8*k]);
}

// ---------------- V slice transpose bf16 [s][h] -> [h][s] ----------------
__global__ void trans_v(const unsigned short* __restrict__ qkv, unsigned short* __restrict__ vT) {
  __shared__ unsigned short tile[32][33];
  int slice = blockIdx.z;           // b*4+kh
  int s0 = blockIdx.x * 32, h0 = blockIdx.y * 32;
  int tx = threadIdx.x, ty = threadIdx.y;
  const unsigned short* in = qkv + (size_t)(slice >> 2) * TT * QKVC + (NHC + KHC) + (slice & 3) * HD;
  unsigned short* out = vT + (size_t)slice * HD * TT;
  #pragma unroll
  for (int k = 0; k < 4; k++)
    tile[ty + 8*k][tx] = in[(size_t)(s0 + ty + 8*k) * QKVC + h0 + tx];
  __syncthreads();
  #pragma unroll
  for (int k = 0; k < 4; k++)
    out[(size_t)(h0 + ty + 8*k) * TT + s0 + tx] = tile[tx][ty + 8*k];
}

// ---------------- RoPE sin/cos table (fp64 precision) ----------------
__global__ void sincos_init(float* __restrict__ stab, float* __restrict__ ctab) {
  int idx = blockIdx.x * 256 + threadIdx.x;
  if (idx >= TT * 64) return;
  int t = idx >> 6, i = idx & 63;
  double inv = exp(-log(10000.0) * ((double)i / 64.0));
  double ang = (double)t * inv;
  stab[idx] = (float)sin(ang);
  ctab[idx] = (float)cos(ang);
}

// ---------------- NT GEMM: C[M][Nn] = A[M][Kd] * Bt[Nn][Kd]^T (bf16 in, fp32 acc) ----------------
template<int OUTBF16>
__global__ __launch_bounds__(256) void gemm_nt(
    const unsigned short* __restrict__ A, const unsigned short* __restrict__ Bt,
    void* __restrict__ outp, int M, int Nn, int Kd) {
  constexpr int PIT = 40;                       // padded pitch (bf16): 80B rows, 16B aligned, conflict-free-ish
  __shared__ unsigned short As[128 * PIT];
  __shared__ unsigned short Bs[128 * PIT];
  int tid = threadIdx.x;
  int wave = tid >> 6, lane = tid & 63, q4 = lane >> 4, l16 = lane & 15;
  int m0 = blockIdx.y * 128, n0 = blockIdx.x * 128;
  int wm = (wave & 1) * 64, wn = (wave >> 1) * 64;
  f32x4 acc[4][4];
  #pragma unroll
  for (int i = 0; i < 4; i++)
    #pragma unroll
    for (int j = 0; j < 4; j++) acc[i][j] = f32x4{0.f, 0.f, 0.f, 0.f};
  int srow = tid >> 2, sc = (tid & 3) * 8;
  const unsigned short* Ag = A + (size_t)(m0 + srow) * Kd + sc;
  const unsigned short* Bg = Bt + (size_t)(n0 + srow) * Kd + sc;
  size_t stride64 = (size_t)64 * Kd;
  for (int k0 = 0; k0 < Kd; k0 += 32) {
    uint4 a0 = *(const uint4*)(Ag + k0);
    uint4 a1 = *(const uint4*)(Ag + stride64 + k0);
    uint4 b0 = *(const uint4*)(Bg + k0);
    uint4 b1 = *(const uint4*)(Bg + stride64 + k0);
    __syncthreads();
    *(uint4*)&As[srow * PIT + sc] = a0;
    *(uint4*)&As[(64 + srow) * PIT + sc] = a1;
    *(uint4*)&Bs[srow * PIT + sc] = b0;
    *(uint4*)&Bs[(64 + srow) * PIT + sc] = b1;
    __syncthreads();
    s16x8 af[4], bfr[4];
    #pragma unroll
    for (int mf = 0; mf < 4; mf++)
      af[mf] = *(const s16x8*)&As[(wm + mf*16 + l16) * PIT + q4 * 8];
    #pragma unroll
    for (int nf = 0; nf < 4; nf++)
      bfr[nf] = *(const s16x8*)&Bs[(wn + nf*16 + l16) * PIT + q4 * 8];
    #pragma unroll
    for (int mf = 0; mf < 4; mf++)
      #pragma unroll
      for (int nf = 0; nf < 4; nf++)
        acc[mf][nf] = __builtin_amdgcn_mfma_f32_16x16x32_bf16(af[mf], bfr[nf], acc[mf][nf], 0, 0, 0);
  }
  #pragma unroll
  for (int mf = 0; mf < 4; mf++)
    #pragma unroll
    for (int nf = 0; nf < 4; nf++)
      #pragma unroll
      for (int r = 0; r < 4; r++) {
        int row = m0 + wm + mf*16 + q4*4 + r;
        int col = n0 + wn + nf*16 + l16;
        float v = acc[mf][nf][r];
        if (OUTBF16) ((unsigned short*)outp)[(size_t)row * Nn + col] = f2bf(v);
        else         ((float*)outp)[(size_t)row * Nn + col] = v;
      }
}

// ---------------- RMSNorm + RoPE + scale ----------------
__global__ __launch_bounds__(256) void postproc(
    const unsigned short* __restrict__ qkv, unsigned short* __restrict__ qr,
    unsigned short* __restrict__ kr, const float* __restrict__ stab, const float* __restrict__ ctab) {
  __shared__ float sh[NHC + KHC];
  __shared__ float redq[4], redk[4];
  int row = blockIdx.x;
  int t = row & (TT - 1);
  int tid = threadIdx.x;
  const unsigned short* base = qkv + (size_t)row * QKVC;
  float sq = 0.f, sk = 0.f;
  uint4 qv = *(const uint4*)&base[tid * 8];
  const unsigned short* qp = (const unsigned short*)&qv;
  #pragma unroll
  for (int i = 0; i < 8; i++) { float f = bf2f(qp[i]); sh[tid*8 + i] = f; sq += f*f; }
  unsigned kv = *(const unsigned*)&base[NHC + tid*2];
  {
    float f0 = bf2f((unsigned short)(kv & 0xffff));
    float f1 = bf2f((unsigned short)(kv >> 16));
    sh[NHC + tid*2] = f0; sh[NHC + tid*2 + 1] = f1;
    sk += f0*f0 + f1*f1;
  }
  #pragma unroll
  for (int off = 32; off > 0; off >>= 1) { sq += __shfl_xor(sq, off); sk += __shfl_xor(sk, off); }
  if ((tid & 63) == 0) { redq[tid >> 6] = sq; redk[tid >> 6] = sk; }
  __syncthreads();
  float fq = rsqrtf((redq[0]+redq[1]+redq[2]+redq[3]) * (1.f/NHC) + 1e-6f) * 0.08838834764831845f;
  float fk = rsqrtf((redk[0]+redk[1]+redk[2]+redk[3]) * (1.f/KHC) + 1e-6f);
  #pragma unroll
  for (int pi = 0; pi < 4; pi++) {
    int P = pi * 256 + tid;
    int head = P >> 6, i = P & 63;
    float s = stab[t*64 + i], c = ctab[t*64 + i];
    float x1 = sh[head*128 + i], x2 = sh[head*128 + i + 64];
    qr[(size_t)row * NHC + head*128 + i]      = f2bf((x1*c - x2*s) * fq);
    qr[(size_t)row * NHC + head*128 + i + 64] = f2bf((x2*c + x1*s) * fq);
  }
  {
    int head = tid >> 6, i = tid & 63;
    float s = stab[t*64 + i], c = ctab[t*64 + i];
    float x1 = sh[NHC + head*128 + i], x2 = sh[NHC + head*128 + i + 64];
    kr[(size_t)row * KHC + head*128 + i]      = f2bf((x1*c - x2*s) * fk);
    kr[(size_t)row * KHC + head*128 + i + 64] = f2bf((x2*c + x1*s) * fk);
  }
}

// ---------------- flash attention ----------------
// grid: B * NHEAD * (T/128); block 256 (4 waves, 32 q-rows each)
__global__ __launch_bounds__(256) void attn(
    const unsigned short* __restrict__ qr, const unsigned short* __restrict__ kr,
    const unsigned short* __restrict__ vT, unsigned short* __restrict__ enc) {
  constexpr int PIT = 136;               // padded pitch: 272B rows, 16B aligned, 2-way banks max
  __shared__ unsigned short Qs[128 * PIT];   // reused as Ps after Q-frag hoist
  __shared__ unsigned short Ks[128 * PIT];
  __shared__ unsigned short Vs[128 * PIT];   // V^T tile: [h][s]
  int tid = threadIdx.x;
  int wave = tid >> 6, lane = tid & 63, q4 = lane >> 4, l16 = lane & 15;
  int bid = blockIdx.x;
  int qt = bid & 15, n = (bid >> 4) & 15, b = bid >> 8;
  int kh = n >> 2;

  {  // stage Q tile [q 128][h 128]
    size_t qbase = ((size_t)(b * TT + qt * 128)) * NHC + n * HD;
    #pragma unroll
    for (int c2 = 0; c2 < 8; c2++) {
      int flat = c2 * 256 + tid;
      int r = flat >> 4, h0 = (flat & 15) * 8;
      *(uint4*)&Qs[r * PIT + h0] = *(const uint4*)&qr[qbase + (size_t)r * NHC + h0];
    }
  }
  __syncthreads();
  // hoist Q fragments into registers; Qs LDS becomes free (reused as Ps)
  s16x8 af[2][4];
  #pragma unroll
  for (int mf = 0; mf < 2; mf++)
    #pragma unroll
    for (int ks = 0; ks < 4; ks++)
      af[mf][ks] = *(const s16x8*)&Qs[(wave*32 + mf*16 + l16) * PIT + ks*32 + q4*8];

  float m_st[2][4], l_st[2][4];
  f32x4 O[2][8];
  #pragma unroll
  for (int mf = 0; mf < 2; mf++)
    #pragma unroll
    for (int r = 0; r < 4; r++) { m_st[mf][r] = -1e30f; l_st[mf][r] = 0.f; }
  #pragma unroll
  for (int mf = 0; mf < 2; mf++)
    #pragma unroll
    for (int hf = 0; hf < 8; hf++) O[mf][hf] = f32x4{0.f, 0.f, 0.f, 0.f};

  for (int j = 0; j < 16; j++) {
    __syncthreads();
    {  // stage K [s][h] and V^T [h][s] tiles
      size_t kbase = ((size_t)(b * TT + j * 128)) * KHC + kh * HD;
      size_t vbase = ((size_t)((b * 4 + kh) * HD)) * TT + j * 128;
      #pragma unroll
      for (int c2 = 0; c2 < 8; c2++) {
        int flat = c2 * 256 + tid;
        int r = flat >> 4, h0 = (flat & 15) * 8;
        *(uint4*)&Ks[r * PIT + h0] = *(const uint4*)&kr[kbase + (size_t)r * KHC + h0];
        *(uint4*)&Vs[r * PIT + h0] = *(const uint4*)&vT[vbase + (size_t)r * TT + h0];
      }
    }
    __syncthreads();
    // S = Q K^T  (32 q-rows x 128 s-cols per wave)
    f32x4 S[2][8];
    #pragma unroll
    for (int mf = 0; mf < 2; mf++)
      #pragma unroll
      for (int sf = 0; sf < 8; sf++) S[mf][sf] = f32x4{0.f, 0.f, 0.f, 0.f};
    #pragma unroll
    for (int sf = 0; sf < 8; sf++) {
      #pragma unroll
      for (int ks = 0; ks < 4; ks++) {
        s16x8 bfr = *(const s16x8*)&Ks[(sf*16 + l16) * PIT + ks*32 + q4*8];
        S[0][sf] = __builtin_amdgcn_mfma_f32_16x16x32_bf16(af[0][ks], bfr, S[0][sf], 0, 0, 0);
        S[1][sf] = __builtin_amdgcn_mfma_f32_16x16x32_bf16(af[1][ks], bfr, S[1][sf], 0, 0, 0);
      }
    }
    // online softmax (row = q4*4+r within 16; cols spread over 16 lanes)
    #pragma unroll
    for (int mf = 0; mf < 2; mf++) {
      float mx[4], alpha[4], rs[4];
      #pragma unroll
      for (int r = 0; r < 4; r++) {
        float m = S[mf][0][r];
        #pragma unroll
        for (int sf = 1; sf < 8; sf++) m = fmaxf(m, S[mf][sf][r]);
        mx[r] = m;
      }
      #pragma unroll
      for (int off = 1; off < 16; off <<= 1)
        #pragma unroll
        for (int r = 0; r < 4; r++) mx[r] = fmaxf(mx[r], __shfl_xor(mx[r], off));
      #pragma unroll
      for (int r = 0; r < 4; r++) {
        float mn = fmaxf(m_st[mf][r], mx[r]);
        alpha[r] = __expf(m_st[mf][r] - mn);
        m_st[mf][r] = mn;
        rs[r] = 0.f;
      }
      #pragma unroll
      for (int sf = 0; sf < 8; sf++)
        #pragma unroll
        for (int r = 0; r < 4; r++) {
          float p = __expf(S[mf][sf][r] - m_st[mf][r]);
          S[mf][sf][r] = p;
          rs[r] += p;
        }
      #pragma unroll
      for (int off = 1; off < 16; off <<= 1)
        #pragma unroll
        for (int r = 0; r < 4; r++) rs[r] += __shfl_xor(rs[r], off);
      #pragma unroll
      for (int r = 0; r < 4; r++) l_st[mf][r] = l_st[mf][r] * alpha[r] + rs[r];
      #pragma unroll
      for (int hf = 0; hf < 8; hf++)
        #pragma unroll
        for (int r = 0; r < 4; r++) O[mf][hf][r] *= alpha[r];
      // P (bf16) -> LDS in A-operand-friendly row-major layout (reusing Qs)
      #pragma unroll
      for (int sf = 0; sf < 8; sf++)
        #pragma unroll
        for (int r = 0; r < 4; r++)
          Qs[(wave*32 + mf*16 + q4*4 + r) * PIT + sf*16 + l16] = f2bf(S[mf][sf][r]);
    }
    __syncthreads();
    // O += P V
    #pragma unroll
    for (int ks = 0; ks < 4; ks++) {
      s16x8 pa[2];
      #pragma unroll
      for (int mf = 0; mf < 2; mf++)
        pa[mf] = *(const s16x8*)&Qs[(wave*32 + mf*16 + l16) * PIT + ks*32 + q4*8];
      #pragma unroll
      for (int hf = 0; hf < 8; hf++) {
        s16x8 vb = *(const s16x8*)&Vs[(hf*16 + l16) * PIT + ks*32 + q4*8];
        O[0][hf] = __builtin_amdgcn_mfma_f32_16x16x32_bf16(pa[0], vb, O[0][hf], 0, 0, 0);
        O[1][hf] = __builtin_amdgcn_mfma_f32_16x16x32_bf16(pa[1], vb, O[1][hf], 0, 0, 0);
      }
    }
  }
  // epilogue: O /= l, write enc
  #pragma unroll
  for (int mf = 0; mf < 2; mf++) {
    float inv[4];
    #pragma unroll
    for (int r = 0; r < 4; r++) inv[r] = 1.f / l_st[mf][r];
    #pragma unroll
    for (int hf = 0; hf < 8; hf++)
      #pragma unroll
      for (int r = 0; r < 4; r++) {
        int t = qt*128 + wave*32 + mf*16 + q4*4 + r;
        enc[((size_t)(b*TT + t)) * NHC + n*HD + hf*16 + l16] = f2bf(O[mf][hf][r] * inv[r]);
      }
  }
}

extern "C" void kernel_launch(void* const* d_in, const int* in_sizes, int n_in,
                              void* d_out, int out_size, void* d_ws, size_t ws_size,
                              hipStream_t stream) {
  const float* x  = (const float*)d_in[0];
  const float* Wq = (const float*)d_in[1];
  const float* Wk = (const float*)d_in[2];
  const float* Wv = (const float*)d_in[3];
  const float* Wo = (const float*)d_in[4];
  float* out = (float*)d_out;

  char* ws = (char*)d_ws;
  size_t off = 0;
  auto alloc = [&](size_t bytes) -> void* {
    void* p = ws + off;
    off += (bytes + 255) & ~(size_t)255;
    return p;
  };
  unsigned short* xb    = (unsigned short*)alloc((size_t)BT * CC * 2);
  unsigned short* wqkvt = (unsigned short*)alloc((size_t)QKVC * CC * 2);
  unsigned short* wot   = (unsigned short*)alloc((size_t)CC * NHC * 2);
  unsigned short* qkv   = (unsigned short*)alloc((size_t)BT * QKVC * 2);
  unsigned short* qrb   = (unsigned short*)alloc((size_t)BT * NHC * 2);
  unsigned short* krb   = (unsigned short*)alloc((size_t)BT * KHC * 2);
  unsigned short* vTb   = (unsigned short*)alloc((size_t)BB * KVH * HD * TT * 2);
  unsigned short* encb  = (unsigned short*)alloc((size_t)BT * NHC * 2);
  float* stab = (float*)alloc((size_t)TT * 64 * 4);
  float* ctab = (float*)alloc((size_t)TT * 64 * 4);

  dim3 tb(32, 8);
  // x -> bf16
  cvt_f2b<<<(BT*CC/4 + 255)/256, 256, 0, stream>>>(x, xb, BT*CC/4);
  // W transposes (fp32 -> bf16): Wqkv^T stacked [q 2048 | k 512 | v 512][2048], Wout^T
  trans_f2b<<<dim3(NHC/32, CC/32), tb, 0, stream>>>(Wq, wqkvt, CC, NHC);
  trans_f2b<<<dim3(KHC/32, CC/32), tb, 0, stream>>>(Wk, wqkvt + (size_t)NHC*CC, CC, KHC);
  trans_f2b<<<dim3(KHC/32, CC/32), tb, 0, stream>>>(Wv, wqkvt + (size_t)(NHC+KHC)*CC, CC, KHC);
  trans_f2b<<<dim3(NHC/32, NHC/32), tb, 0, stream>>>(Wo, wot, NHC, CC);
  sincos_init<<<(TT*64 + 255)/256, 256, 0, stream>>>(stab, ctab);
  // qkv = x @ [Wq|Wk|Wv]
  gemm_nt<1><<<dim3(QKVC/128, BT/128), 256, 0, stream>>>(xb, wqkvt, qkv, BT, QKVC, CC);
  // rmsnorm + rope + scale
  postproc<<<BT, 256, 0, stream>>>(qkv, qrb, krb, stab, ctab);
  // v^T per (b, kv-head)
  trans_v<<<dim3(TT/32, HD/32, BB*KVH), tb, 0, stream>>>(qkv, vTb);
  // flash attention
  attn<<<BB * NHEAD * (TT/128), 256, 0, stream>>>(qrb, krb, vTb, encb);
  // out = enc @ Wout
  gemm_nt<0><<<dim3(CC/128, BT/128), 256, 0, stream>>>(encb, wot, out, BT, CC, NHC);
}

// Round 2
// 638.808 us; speedup vs baseline: 1.6077x; 1.6077x over previous
//
#include <hip/hip_runtime.h>
#include <hip/hip_bf16.h>
#include <math.h>

typedef __attribute__((ext_vector_type(4))) float f32x4;
typedef __attribute__((ext_vector_type(8))) short s16x8;
typedef __attribute__((ext_vector_type(4))) short s16x4;

#define BB 4
#define TT 2048
#define CC 2048
#define NHEAD 16
#define KVH 4
#define HD 128
#define BT (BB*TT)      // 8192
#define NHC 2048        // N*H
#define KHC 512         // K*H
#define QKVC 3072

__device__ __forceinline__ float bf2f(unsigned short u) {
  union { unsigned u; float f; } v; v.u = ((unsigned)u) << 16; return v.f;
}
__device__ __forceinline__ unsigned short f2bf(float f) {
  union { float f; unsigned u; } v; v.f = f;
  unsigned r = v.u + 0x7fff + ((v.u >> 16) & 1);
  return (unsigned short)(r >> 16);
}

// ---- 16x16x16 bf16 MFMA (K=16): P^T-in-registers path ----
#if defined(__has_builtin)
#if __has_builtin(__builtin_amdgcn_mfma_f32_16x16x16bf16_1k)
#define MFMA16(a, b, c) __builtin_amdgcn_mfma_f32_16x16x16bf16_1k((a), (b), (c), 0, 0, 0)
#elif __has_builtin(__builtin_amdgcn_mfma_f32_16x16x16_bf16)
#define MFMA16(a, b, c) __builtin_amdgcn_mfma_f32_16x16x16_bf16((a), (b), (c), 0, 0, 0)
#endif
#endif
#ifndef MFMA16
__device__ __forceinline__ f32x4 mfma16_asm(s16x4 a, s16x4 b, f32x4 c) {
  f32x4 d;
  asm volatile("s_nop 1\n\tv_mfma_f32_16x16x16_bf16 %0, %1, %2, %3"
               : "=v"(d) : "v"(a), "v"(b), "v"(c));
  return d;
}
#define MFMA16(a, b, c) mfma16_asm((a), (b), (c))
#define MFMA16_ASM_FALLBACK 1
#endif

// ---------------- fp32 -> bf16 elementwise ----------------
__global__ void cvt_f2b(const float* __restrict__ in, unsigned short* __restrict__ out, int n4) {
  int i = blockIdx.x * 256 + threadIdx.x;
  if (i >= n4) return;
  float4 v = ((const float4*)in)[i];
  ushort4 o;
  o.x = f2bf(v.x); o.y = f2bf(v.y); o.z = f2bf(v.z); o.w = f2bf(v.w);
  ((ushort4*)out)[i] = o;
}

// ---------------- fp32 [R][Cc] -> bf16 [Cc][R] transpose ----------------
__global__ void trans_f2b(const float* __restrict__ in, unsigned short* __restrict__ out, int R, int Cc) {
  __shared__ float tile[32][33];
  int c0 = blockIdx.x * 32, r0 = blockIdx.y * 32;
  int tx = threadIdx.x, ty = threadIdx.y;
  #pragma unroll
  for (int k = 0; k < 4; k++)
    tile[ty + 8*k][tx] = in[(size_t)(r0 + ty + 8*k) * Cc + c0 + tx];
  __syncthreads();
  #pragma unroll
  for (int k = 0; k < 4; k++)
    out[(size_t)(c0 + ty + 8*k) * R + r0 + tx] = f2bf(tile[tx][ty + 8*k]);
}

// ---------------- V slice transpose bf16 [s][h] -> [h][s] ----------------
__global__ void trans_v(const unsigned short* __restrict__ qkv, unsigned short* __restrict__ vT) {
  __shared__ unsigned short tile[32][33];
  int slice = blockIdx.z;           // b*4+kh
  int s0 = blockIdx.x * 32, h0 = blockIdx.y * 32;
  int tx = threadIdx.x, ty = threadIdx.y;
  const unsigned short* in = qkv + (size_t)(slice >> 2) * TT * QKVC + (NHC + KHC) + (slice & 3) * HD;
  unsigned short* out = vT + (size_t)slice * HD * TT;
  #pragma unroll
  for (int k = 0; k < 4; k++)
    tile[ty + 8*k][tx] = in[(size_t)(s0 + ty + 8*k) * QKVC + h0 + tx];
  __syncthreads();
  #pragma unroll
  for (int k = 0; k < 4; k++)
    out[(size_t)(h0 + ty + 8*k) * TT + s0 + tx] = tile[tx][ty + 8*k];
}

// ---------------- RoPE sin/cos table (fp64 precision) ----------------
__global__ void sincos_init(float* __restrict__ stab, float* __restrict__ ctab) {
  int idx = blockIdx.x * 256 + threadIdx.x;
  if (idx >= TT * 64) return;
  int t = idx >> 6, i = idx & 63;
  double inv = exp(-log(10000.0) * ((double)i / 64.0));
  double ang = (double)t * inv;
  stab[idx] = (float)sin(ang);
  ctab[idx] = (float)cos(ang);
}

// ---------------- NT GEMM: C[M][Nn] = A[M][Kd] * Bt[Nn][Kd]^T (bf16 in, fp32 acc) ----------------
template<int OUTBF16>
__global__ __launch_bounds__(256) void gemm_nt(
    const unsigned short* __restrict__ A, const unsigned short* __restrict__ Bt,
    void* __restrict__ outp, int M, int Nn, int Kd) {
  constexpr int PIT = 40;
  __shared__ unsigned short As[128 * PIT];
  __shared__ unsigned short Bs[128 * PIT];
  int tid = threadIdx.x;
  int wave = tid >> 6, lane = tid & 63, q4 = lane >> 4, l16 = lane & 15;
  int m0 = blockIdx.y * 128, n0 = blockIdx.x * 128;
  int wm = (wave & 1) * 64, wn = (wave >> 1) * 64;
  f32x4 acc[4][4];
  #pragma unroll
  for (int i = 0; i < 4; i++)
    #pragma unroll
    for (int j = 0; j < 4; j++) acc[i][j] = f32x4{0.f, 0.f, 0.f, 0.f};
  int srow = tid >> 2, sc = (tid & 3) * 8;
  const unsigned short* Ag = A + (size_t)(m0 + srow) * Kd + sc;
  const unsigned short* Bg = Bt + (size_t)(n0 + srow) * Kd + sc;
  size_t stride64 = (size_t)64 * Kd;
  for (int k0 = 0; k0 < Kd; k0 += 32) {
    uint4 a0 = *(const uint4*)(Ag + k0);
    uint4 a1 = *(const uint4*)(Ag + stride64 + k0);
    uint4 b0 = *(const uint4*)(Bg + k0);
    uint4 b1 = *(const uint4*)(Bg + stride64 + k0);
    __syncthreads();
    *(uint4*)&As[srow * PIT + sc] = a0;
    *(uint4*)&As[(64 + srow) * PIT + sc] = a1;
    *(uint4*)&Bs[srow * PIT + sc] = b0;
    *(uint4*)&Bs[(64 + srow) * PIT + sc] = b1;
    __syncthreads();
    s16x8 af[4], bfr[4];
    #pragma unroll
    for (int mf = 0; mf < 4; mf++)
      af[mf] = *(const s16x8*)&As[(wm + mf*16 + l16) * PIT + q4 * 8];
    #pragma unroll
    for (int nf = 0; nf < 4; nf++)
      bfr[nf] = *(const s16x8*)&Bs[(wn + nf*16 + l16) * PIT + q4 * 8];
    #pragma unroll
    for (int mf = 0; mf < 4; mf++)
      #pragma unroll
      for (int nf = 0; nf < 4; nf++)
        acc[mf][nf] = __builtin_amdgcn_mfma_f32_16x16x32_bf16(af[mf], bfr[nf], acc[mf][nf], 0, 0, 0);
  }
  #pragma unroll
  for (int mf = 0; mf < 4; mf++)
    #pragma unroll
    for (int nf = 0; nf < 4; nf++)
      #pragma unroll
      for (int r = 0; r < 4; r++) {
        int row = m0 + wm + mf*16 + q4*4 + r;
        int col = n0 + wn + nf*16 + l16;
        float v = acc[mf][nf][r];
        if (OUTBF16) ((unsigned short*)outp)[(size_t)row * Nn + col] = f2bf(v);
        else         ((float*)outp)[(size_t)row * Nn + col] = v;
      }
}

// ---------------- RMSNorm + RoPE + scale ----------------
__global__ __launch_bounds__(256) void postproc(
    const unsigned short* __restrict__ qkv, unsigned short* __restrict__ qr,
    unsigned short* __restrict__ kr, const float* __restrict__ stab, const float* __restrict__ ctab) {
  __shared__ float sh[NHC + KHC];
  __shared__ float redq[4], redk[4];
  int row = blockIdx.x;
  int t = row & (TT - 1);
  int tid = threadIdx.x;
  const unsigned short* base = qkv + (size_t)row * QKVC;
  float sq = 0.f, sk = 0.f;
  uint4 qv = *(const uint4*)&base[tid * 8];
  const unsigned short* qp = (const unsigned short*)&qv;
  #pragma unroll
  for (int i = 0; i < 8; i++) { float f = bf2f(qp[i]); sh[tid*8 + i] = f; sq += f*f; }
  unsigned kv = *(const unsigned*)&base[NHC + tid*2];
  {
    float f0 = bf2f((unsigned short)(kv & 0xffff));
    float f1 = bf2f((unsigned short)(kv >> 16));
    sh[NHC + tid*2] = f0; sh[NHC + tid*2 + 1] = f1;
    sk += f0*f0 + f1*f1;
  }
  #pragma unroll
  for (int off = 32; off > 0; off >>= 1) { sq += __shfl_xor(sq, off); sk += __shfl_xor(sk, off); }
  if ((tid & 63) == 0) { redq[tid >> 6] = sq; redk[tid >> 6] = sk; }
  __syncthreads();
  float fq = rsqrtf((redq[0]+redq[1]+redq[2]+redq[3]) * (1.f/NHC) + 1e-6f) * 0.08838834764831845f;
  float fk = rsqrtf((redk[0]+redk[1]+redk[2]+redk[3]) * (1.f/KHC) + 1e-6f);
  #pragma unroll
  for (int pi = 0; pi < 4; pi++) {
    int P = pi * 256 + tid;
    int head = P >> 6, i = P & 63;
    float s = stab[t*64 + i], c = ctab[t*64 + i];
    float x1 = sh[head*128 + i], x2 = sh[head*128 + i + 64];
    qr[(size_t)row * NHC + head*128 + i]      = f2bf((x1*c - x2*s) * fq);
    qr[(size_t)row * NHC + head*128 + i + 64] = f2bf((x2*c + x1*s) * fq);
  }
  {
    int head = tid >> 6, i = tid & 63;
    float s = stab[t*64 + i], c = ctab[t*64 + i];
    float x1 = sh[NHC + head*128 + i], x2 = sh[NHC + head*128 + i + 64];
    kr[(size_t)row * KHC + head*128 + i]      = f2bf((x1*c - x2*s) * fk);
    kr[(size_t)row * KHC + head*128 + i + 64] = f2bf((x2*c + x1*s) * fk);
  }
}

// ---------------- flash attention v2: S^T layout, direct register P feed ----------------
// grid: B*NHEAD*(T/128) blocks of 256 (4 waves); wave handles 32 q (2 q-blocks of 16)
// LDS: Ks[128s][128h], Vs(V^T)[128h][128s], both XOR-swizzled at 8-short-chunk granularity
__global__ __launch_bounds__(256, 2) void attn(
    const unsigned short* __restrict__ qr, const unsigned short* __restrict__ kr,
    const unsigned short* __restrict__ vT, unsigned short* __restrict__ enc) {
  __shared__ unsigned short Ks[128 * 128];
  __shared__ unsigned short Vs[128 * 128];
  int tid = threadIdx.x;
  int wave = tid >> 6, lane = tid & 63, q4 = lane >> 4, l16 = lane & 15;
  int bid = blockIdx.x;
  int qt = bid & 15, n = (bid >> 4) & 15, b = bid >> 8, kh = n >> 2;

  // ---- stage Q tile into Ks (swizzled), hoist B-frags, then Ks is reused for K ----
  {
    size_t qbase = ((size_t)(b * TT + qt * 128)) * NHC + n * HD;
    #pragma unroll
    for (int c2 = 0; c2 < 8; c2++) {
      int flat = c2 * 256 + tid;               // 2048 16B-chunks
      int r = flat >> 4, c = flat & 15;
      *(uint4*)&Ks[r * 128 + ((c ^ (r & 7)) << 3)] =
          *(const uint4*)&qr[qbase + (size_t)r * NHC + (c << 3)];
    }
  }
  __syncthreads();
  s16x8 qf[2][4];   // B-operand frags: n=q=l16, k=h
  #pragma unroll
  for (int qb = 0; qb < 2; qb++)
    #pragma unroll
    for (int ku = 0; ku < 4; ku++) {
      int r = wave * 32 + qb * 16 + l16;
      qf[qb][ku] = *(const s16x8*)&Ks[r * 128 + (((ku * 4 + q4) ^ (r & 7)) << 3)];
    }

  float m_st[2] = {-1e30f, -1e30f}, l_st[2] = {0.f, 0.f};
  f32x4 O[2][8];
  #pragma unroll
  for (int qb = 0; qb < 2; qb++)
    #pragma unroll
    for (int hb = 0; hb < 8; hb++) O[qb][hb] = f32x4{0.f, 0.f, 0.f, 0.f};

  for (int j = 0; j < 16; j++) {
    __syncthreads();     // everyone done reading Ks (Q-frags or prev K) and Vs
    {
      size_t kbase = ((size_t)(b * TT + j * 128)) * KHC + kh * HD;
      size_t vbase = ((size_t)((b * KVH + kh) * HD)) * TT + j * 128;
      #pragma unroll
      for (int c2 = 0; c2 < 8; c2++) {
        int flat = c2 * 256 + tid;
        int r = flat >> 4, c = flat & 15;
        int sw = (c ^ (r & 7)) << 3;
        *(uint4*)&Ks[r * 128 + sw] = *(const uint4*)&kr[kbase + (size_t)r * KHC + (c << 3)];
        *(uint4*)&Vs[r * 128 + sw] = *(const uint4*)&vT[vbase + (size_t)r * TT + (c << 3)];
      }
    }
    __syncthreads();
    // ---- S^T = K Q^T : D[m=s][n=q] ----
    f32x4 S[2][8];
    #pragma unroll
    for (int qb = 0; qb < 2; qb++)
      #pragma unroll
      for (int mb = 0; mb < 8; mb++) S[qb][mb] = f32x4{0.f, 0.f, 0.f, 0.f};
    #pragma unroll
    for (int mb = 0; mb < 8; mb++) {
      int r = mb * 16 + l16;
      #pragma unroll
      for (int ku = 0; ku < 4; ku++) {
        s16x8 kf = *(const s16x8*)&Ks[r * 128 + (((ku * 4 + q4) ^ (r & 7)) << 3)];
        S[0][mb] = __builtin_amdgcn_mfma_f32_16x16x32_bf16(kf, qf[0][ku], S[0][mb], 0, 0, 0);
        S[1][mb] = __builtin_amdgcn_mfma_f32_16x16x32_bf16(kf, qf[1][ku], S[1][mb], 0, 0, 0);
      }
    }
    // ---- online softmax: per lane q = l16 fixed; s = mb*16 + q4*4 + r ----
    s16x4 pf[2][8];
    #pragma unroll
    for (int qb = 0; qb < 2; qb++) {
      float mx = -1e30f;
      #pragma unroll
      for (int mb = 0; mb < 8; mb++)
        #pragma unroll
        for (int r = 0; r < 4; r++) mx = fmaxf(mx, S[qb][mb][r]);
      mx = fmaxf(mx, __shfl_xor(mx, 16));
      mx = fmaxf(mx, __shfl_xor(mx, 32));
      float mn = fmaxf(m_st[qb], mx);
      float alpha = __expf(m_st[qb] - mn);
      m_st[qb] = mn;
      float rs = 0.f;
      #pragma unroll
      for (int mb = 0; mb < 8; mb++)
        #pragma unroll
        for (int r = 0; r < 4; r++) {
          float p = __expf(S[qb][mb][r] - mn);
          rs += p;
          pf[qb][mb][r] = (short)f2bf(p);
        }
      rs += __shfl_xor(rs, 16);
      rs += __shfl_xor(rs, 32);
      l_st[qb] = l_st[qb] * alpha + rs;
      #pragma unroll
      for (int hb = 0; hb < 8; hb++) O[qb][hb] *= alpha;
    }
    // ---- O^T[h][q] += V^T[h][s] P^T[s][q] via 16x16x16 (P^T direct from regs) ----
    #pragma unroll
    for (int su = 0; su < 8; su++) {
      #pragma unroll
      for (int hb = 0; hb < 8; hb++) {
        int r = hb * 16 + l16;
        int col4 = su * 4 + q4;    // s-group of 4
        s16x4 vf = *(const s16x4*)&Vs[r * 128 + (((col4 >> 1) ^ (r & 7)) << 3) + ((col4 & 1) << 2)];
        O[0][hb] = MFMA16(vf, pf[0][su], O[0][hb]);
        O[1][hb] = MFMA16(vf, pf[1][su], O[1][hb]);
      }
    }
  }
#ifdef MFMA16_ASM_FALLBACK
  asm volatile("s_nop 7\n\ts_nop 7\n\ts_nop 7" ::: "memory");
#endif
  // ---- epilogue: O^T layout col q=l16, row h=q4*4+r within hb-block ----
  #pragma unroll
  for (int qb = 0; qb < 2; qb++) {
    float inv = 1.f / l_st[qb];
    int t = b * TT + qt * 128 + wave * 32 + qb * 16 + l16;
    #pragma unroll
    for (int hb = 0; hb < 8; hb++) {
      ushort4 o;
      o.x = f2bf(O[qb][hb][0] * inv);
      o.y = f2bf(O[qb][hb][1] * inv);
      o.z = f2bf(O[qb][hb][2] * inv);
      o.w = f2bf(O[qb][hb][3] * inv);
      *(ushort4*)&enc[(size_t)t * NHC + n * HD + hb * 16 + q4 * 4] = o;
    }
  }
}

extern "C" void kernel_launch(void* const* d_in, const int* in_sizes, int n_in,
                              void* d_out, int out_size, void* d_ws, size_t ws_size,
                              hipStream_t stream) {
  const float* x  = (const float*)d_in[0];
  const float* Wq = (const float*)d_in[1];
  const float* Wk = (const float*)d_in[2];
  const float* Wv = (const float*)d_in[3];
  const float* Wo = (const float*)d_in[4];
  float* out = (float*)d_out;

  char* ws = (char*)d_ws;
  size_t off = 0;
  auto alloc = [&](size_t bytes) -> void* {
    void* p = ws + off;
    off += (bytes + 255) & ~(size_t)255;
    return p;
  };
  unsigned short* xb    = (unsigned short*)alloc((size_t)BT * CC * 2);
  unsigned short* wqkvt = (unsigned short*)alloc((size_t)QKVC * CC * 2);
  unsigned short* wot   = (unsigned short*)alloc((size_t)CC * NHC * 2);
  unsigned short* qkv   = (unsigned short*)alloc((size_t)BT * QKVC * 2);
  unsigned short* qrb   = (unsigned short*)alloc((size_t)BT * NHC * 2);
  unsigned short* krb   = (unsigned short*)alloc((size_t)BT * KHC * 2);
  unsigned short* vTb   = (unsigned short*)alloc((size_t)BB * KVH * HD * TT * 2);
  unsigned short* encb  = (unsigned short*)alloc((size_t)BT * NHC * 2);
  float* stab = (float*)alloc((size_t)TT * 64 * 4);
  float* ctab = (float*)alloc((size_t)TT * 64 * 4);

  dim3 tb(32, 8);
  cvt_f2b<<<(BT*CC/4 + 255)/256, 256, 0, stream>>>(x, xb, BT*CC/4);
  trans_f2b<<<dim3(NHC/32, CC/32), tb, 0, stream>>>(Wq, wqkvt, CC, NHC);
  trans_f2b<<<dim3(KHC/32, CC/32), tb, 0, stream>>>(Wk, wqkvt + (size_t)NHC*CC, CC, KHC);
  trans_f2b<<<dim3(KHC/32, CC/32), tb, 0, stream>>>(Wv, wqkvt + (size_t)(NHC+KHC)*CC, CC, KHC);
  trans_f2b<<<dim3(NHC/32, NHC/32), tb, 0, stream>>>(Wo, wot, NHC, CC);
  sincos_init<<<(TT*64 + 255)/256, 256, 0, stream>>>(stab, ctab);
  gemm_nt<1><<<dim3(QKVC/128, BT/128), 256, 0, stream>>>(xb, wqkvt, qkv, BT, QKVC, CC);
  postproc<<<BT, 256, 0, stream>>>(qkv, qrb, krb, stab, ctab);
  trans_v<<<dim3(TT/32, HD/32, BB*KVH), tb, 0, stream>>>(qkv, vTb);
  attn<<<BB * NHEAD * (TT/128), 256, 0, stream>>>(qrb, krb, vTb, encb);
  gemm_nt<0><<<dim3(CC/128, BT/128), 256, 0, stream>>>(encb, wot, out, BT, CC, NHC);
}

// Round 3
// 632.175 us; speedup vs baseline: 1.6245x; 1.0105x over previous
//
#include <hip/hip_runtime.h>
#include <hip/hip_bf16.h>
#include <math.h>

typedef __attribute__((ext_vector_type(4))) float f32x4;
typedef __attribute__((ext_vector_type(8))) short s16x8;
typedef __attribute__((ext_vector_type(4))) short s16x4;

#define BB 4
#define TT 2048
#define CC 2048
#define NHEAD 16
#define KVH 4
#define HD 128
#define BT (BB*TT)      // 8192
#define NHC 2048        // N*H
#define KHC 512         // K*H
#define QKVC 3072

__device__ __forceinline__ float bf2f(unsigned short u) {
  union { unsigned u; float f; } v; v.u = ((unsigned)u) << 16; return v.f;
}
__device__ __forceinline__ unsigned short f2bf(float f) {
  union { float f; unsigned u; } v; v.f = f;
  unsigned r = v.u + 0x7fff + ((v.u >> 16) & 1);
  return (unsigned short)(r >> 16);
}

// ---- async global->LDS 16B (lane i lands at ldsbase + i*16; ldsbase must be wave-uniform) ----
__device__ __forceinline__ void glld16(const void* gsrc, void* ldsbase) {
  __builtin_amdgcn_global_load_lds(
      (const __attribute__((address_space(1))) unsigned int*)gsrc,
      (__attribute__((address_space(3))) unsigned int*)(unsigned int)(unsigned long long)ldsbase,
      16, 0, 0);
}

// ---- 16x16x16 bf16 MFMA (K=16): P^T-in-registers path ----
#if defined(__has_builtin)
#if __has_builtin(__builtin_amdgcn_mfma_f32_16x16x16bf16_1k)
#define MFMA16(a, b, c) __builtin_amdgcn_mfma_f32_16x16x16bf16_1k((a), (b), (c), 0, 0, 0)
#elif __has_builtin(__builtin_amdgcn_mfma_f32_16x16x16_bf16)
#define MFMA16(a, b, c) __builtin_amdgcn_mfma_f32_16x16x16_bf16((a), (b), (c), 0, 0, 0)
#endif
#endif
#ifndef MFMA16
__device__ __forceinline__ f32x4 mfma16_asm(s16x4 a, s16x4 b, f32x4 c) {
  f32x4 d;
  asm volatile("s_nop 1\n\tv_mfma_f32_16x16x16_bf16 %0, %1, %2, %3"
               : "=v"(d) : "v"(a), "v"(b), "v"(c));
  return d;
}
#define MFMA16(a, b, c) mfma16_asm((a), (b), (c))
#define MFMA16_ASM_FALLBACK 1
#endif

// ---------------- fp32 -> bf16 elementwise ----------------
__global__ void cvt_f2b(const float* __restrict__ in, unsigned short* __restrict__ out, int n4) {
  int i = blockIdx.x * 256 + threadIdx.x;
  if (i >= n4) return;
  float4 v = ((const float4*)in)[i];
  ushort4 o;
  o.x = f2bf(v.x); o.y = f2bf(v.y); o.z = f2bf(v.z); o.w = f2bf(v.w);
  ((ushort4*)out)[i] = o;
}

// ---------------- fp32 [R][Cc] -> bf16 [Cc][R] transpose ----------------
__global__ void trans_f2b(const float* __restrict__ in, unsigned short* __restrict__ out, int R, int Cc) {
  __shared__ float tile[32][33];
  int c0 = blockIdx.x * 32, r0 = blockIdx.y * 32;
  int tx = threadIdx.x, ty = threadIdx.y;
  #pragma unroll
  for (int k = 0; k < 4; k++)
    tile[ty + 8*k][tx] = in[(size_t)(r0 + ty + 8*k) * Cc + c0 + tx];
  __syncthreads();
  #pragma unroll
  for (int k = 0; k < 4; k++)
    out[(size_t)(c0 + ty + 8*k) * R + r0 + tx] = f2bf(tile[tx][ty + 8*k]);
}

// ---------------- V slice transpose bf16 [s][h] -> [h][s] ----------------
__global__ void trans_v(const unsigned short* __restrict__ qkv, unsigned short* __restrict__ vT) {
  __shared__ unsigned short tile[32][33];
  int slice = blockIdx.z;           // b*4+kh
  int s0 = blockIdx.x * 32, h0 = blockIdx.y * 32;
  int tx = threadIdx.x, ty = threadIdx.y;
  const unsigned short* in = qkv + (size_t)(slice >> 2) * TT * QKVC + (NHC + KHC) + (slice & 3) * HD;
  unsigned short* out = vT + (size_t)slice * HD * TT;
  #pragma unroll
  for (int k = 0; k < 4; k++)
    tile[ty + 8*k][tx] = in[(size_t)(s0 + ty + 8*k) * QKVC + h0 + tx];
  __syncthreads();
  #pragma unroll
  for (int k = 0; k < 4; k++)
    out[(size_t)(h0 + ty + 8*k) * TT + s0 + tx] = tile[tx][ty + 8*k];
}

// ---------------- RoPE sin/cos table (fp64 precision) ----------------
__global__ void sincos_init(float* __restrict__ stab, float* __restrict__ ctab) {
  int idx = blockIdx.x * 256 + threadIdx.x;
  if (idx >= TT * 64) return;
  int t = idx >> 6, i = idx & 63;
  double inv = exp(-log(10000.0) * ((double)i / 64.0));
  double ang = (double)t * inv;
  stab[idx] = (float)sin(ang);
  ctab[idx] = (float)cos(ang);
}

// ---------------- NT GEMM: C[M][Nn] = A[M][Kd] * Bt[Nn][Kd]^T ----------------
// m97-style: global_load_lds dwordx4 staging, 128x128 tile, BK=32, 16 MFMA/wave/iter.
// LDS logical layout [128 rows][4 chunks of 16B], chunk slot holds global chunk
// (slot ^ ((row>>1)&3)) so fragment ds_read_b128 is bank-conflict-free.
template<int OUTBF16>
__global__ __launch_bounds__(256) void gemm_nt(
    const unsigned short* __restrict__ A, const unsigned short* __restrict__ Bt,
    void* __restrict__ outp, int M, int Nn, int Kd) {
  __shared__ unsigned short As[128 * 32];
  __shared__ unsigned short Bs[128 * 32];
  int tid = threadIdx.x;
  int wave = tid >> 6, lane = tid & 63, q4 = lane >> 4, l16 = lane & 15;
  int m0 = blockIdx.y * 128, n0 = blockIdx.x * 128;
  int wm = (wave & 1) * 64, wn = (wave >> 1) * 64;
  f32x4 acc[4][4];
  #pragma unroll
  for (int i = 0; i < 4; i++)
    #pragma unroll
    for (int j = 0; j < 4; j++) acc[i][j] = f32x4{0.f, 0.f, 0.f, 0.f};

  // staging: wave w, instr t in {0,1}: slots s = (w*2+t)*64 + lane
  //   row r = s>>2, chunk-slot = s&3, global chunk cg = (s&3) ^ ((r>>1)&3)
  int r0s = wave * 32 + (lane >> 2);         // t=0 row; t=1 adds 16
  int r1s = r0s + 16;
  int cg0 = (lane & 3) ^ ((r0s >> 1) & 3);
  int cg1 = (lane & 3) ^ ((r1s >> 1) & 3);
  const unsigned short* Ag0 = A + (size_t)(m0 + r0s) * Kd + cg0 * 8;
  const unsigned short* Ag1 = A + (size_t)(m0 + r1s) * Kd + cg1 * 8;
  const unsigned short* Bg0 = Bt + (size_t)(n0 + r0s) * Kd + cg0 * 8;
  const unsigned short* Bg1 = Bt + (size_t)(n0 + r1s) * Kd + cg1 * 8;
  unsigned short* lA0 = As + (wave * 2 + 0) * 512;   // 1 KB per glld
  unsigned short* lA1 = As + (wave * 2 + 1) * 512;
  unsigned short* lB0 = Bs + (wave * 2 + 0) * 512;
  unsigned short* lB1 = Bs + (wave * 2 + 1) * 512;

  // fragment read offsets (shorts): row R = wm/wn + mf*16 + l16, chunk slot = q4 ^ ((R>>1)&3)
  int aoff[4], boff[4];
  #pragma unroll
  for (int f = 0; f < 4; f++) {
    int Ra = wm + f * 16 + l16;
    int Rb = wn + f * 16 + l16;
    aoff[f] = Ra * 32 + (q4 ^ ((Ra >> 1) & 3)) * 8;
    boff[f] = Rb * 32 + (q4 ^ ((Rb >> 1) & 3)) * 8;
  }

  for (int k0 = 0; k0 < Kd; k0 += 32) {
    __syncthreads();
    glld16(Ag0 + k0, lA0);
    glld16(Ag1 + k0, lA1);
    glld16(Bg0 + k0, lB0);
    glld16(Bg1 + k0, lB1);
    asm volatile("s_waitcnt vmcnt(0)" ::: "memory");
    __syncthreads();
    s16x8 af[4], bfr[4];
    #pragma unroll
    for (int mf = 0; mf < 4; mf++) af[mf] = *(const s16x8*)&As[aoff[mf]];
    #pragma unroll
    for (int nf = 0; nf < 4; nf++) bfr[nf] = *(const s16x8*)&Bs[boff[nf]];
    #pragma unroll
    for (int mf = 0; mf < 4; mf++)
      #pragma unroll
      for (int nf = 0; nf < 4; nf++)
        acc[mf][nf] = __builtin_amdgcn_mfma_f32_16x16x32_bf16(af[mf], bfr[nf], acc[mf][nf], 0, 0, 0);
  }
  #pragma unroll
  for (int mf = 0; mf < 4; mf++)
    #pragma unroll
    for (int nf = 0; nf < 4; nf++)
      #pragma unroll
      for (int r = 0; r < 4; r++) {
        int row = m0 + wm + mf*16 + q4*4 + r;
        int col = n0 + wn + nf*16 + l16;
        float v = acc[mf][nf][r];
        if (OUTBF16) ((unsigned short*)outp)[(size_t)row * Nn + col] = f2bf(v);
        else         ((float*)outp)[(size_t)row * Nn + col] = v;
      }
}

// ---------------- RMSNorm + RoPE + scale ----------------
__global__ __launch_bounds__(256) void postproc(
    const unsigned short* __restrict__ qkv, unsigned short* __restrict__ qr,
    unsigned short* __restrict__ kr, const float* __restrict__ stab, const float* __restrict__ ctab) {
  __shared__ float sh[NHC + KHC];
  __shared__ float redq[4], redk[4];
  int row = blockIdx.x;
  int t = row & (TT - 1);
  int tid = threadIdx.x;
  const unsigned short* base = qkv + (size_t)row * QKVC;
  float sq = 0.f, sk = 0.f;
  uint4 qv = *(const uint4*)&base[tid * 8];
  const unsigned short* qp = (const unsigned short*)&qv;
  #pragma unroll
  for (int i = 0; i < 8; i++) { float f = bf2f(qp[i]); sh[tid*8 + i] = f; sq += f*f; }
  unsigned kv = *(const unsigned*)&base[NHC + tid*2];
  {
    float f0 = bf2f((unsigned short)(kv & 0xffff));
    float f1 = bf2f((unsigned short)(kv >> 16));
    sh[NHC + tid*2] = f0; sh[NHC + tid*2 + 1] = f1;
    sk += f0*f0 + f1*f1;
  }
  #pragma unroll
  for (int off = 32; off > 0; off >>= 1) { sq += __shfl_xor(sq, off); sk += __shfl_xor(sk, off); }
  if ((tid & 63) == 0) { redq[tid >> 6] = sq; redk[tid >> 6] = sk; }
  __syncthreads();
  float fq = rsqrtf((redq[0]+redq[1]+redq[2]+redq[3]) * (1.f/NHC) + 1e-6f) * 0.08838834764831845f;
  float fk = rsqrtf((redk[0]+redk[1]+redk[2]+redk[3]) * (1.f/KHC) + 1e-6f);
  #pragma unroll
  for (int pi = 0; pi < 4; pi++) {
    int P = pi * 256 + tid;
    int head = P >> 6, i = P & 63;
    float s = stab[t*64 + i], c = ctab[t*64 + i];
    float x1 = sh[head*128 + i], x2 = sh[head*128 + i + 64];
    qr[(size_t)row * NHC + head*128 + i]      = f2bf((x1*c - x2*s) * fq);
    qr[(size_t)row * NHC + head*128 + i + 64] = f2bf((x2*c + x1*s) * fq);
  }
  {
    int head = tid >> 6, i = tid & 63;
    float s = stab[t*64 + i], c = ctab[t*64 + i];
    float x1 = sh[NHC + head*128 + i], x2 = sh[NHC + head*128 + i + 64];
    kr[(size_t)row * KHC + head*128 + i]      = f2bf((x1*c - x2*s) * fk);
    kr[(size_t)row * KHC + head*128 + i + 64] = f2bf((x2*c + x1*s) * fk);
  }
}

// ---------------- flash attention v2: S^T layout, direct register P feed ----------------
__global__ __launch_bounds__(256, 2) void attn(
    const unsigned short* __restrict__ qr, const unsigned short* __restrict__ kr,
    const unsigned short* __restrict__ vT, unsigned short* __restrict__ enc) {
  __shared__ unsigned short Ks[128 * 128];
  __shared__ unsigned short Vs[128 * 128];
  int tid = threadIdx.x;
  int wave = tid >> 6, lane = tid & 63, q4 = lane >> 4, l16 = lane & 15;
  int bid = blockIdx.x;
  int qt = bid & 15, n = (bid >> 4) & 15, b = bid >> 8, kh = n >> 2;

  {
    size_t qbase = ((size_t)(b * TT + qt * 128)) * NHC + n * HD;
    #pragma unroll
    for (int c2 = 0; c2 < 8; c2++) {
      int flat = c2 * 256 + tid;
      int r = flat >> 4, c = flat & 15;
      *(uint4*)&Ks[r * 128 + ((c ^ (r & 7)) << 3)] =
          *(const uint4*)&qr[qbase + (size_t)r * NHC + (c << 3)];
    }
  }
  __syncthreads();
  s16x8 qf[2][4];
  #pragma unroll
  for (int qb = 0; qb < 2; qb++)
    #pragma unroll
    for (int ku = 0; ku < 4; ku++) {
      int r = wave * 32 + qb * 16 + l16;
      qf[qb][ku] = *(const s16x8*)&Ks[r * 128 + (((ku * 4 + q4) ^ (r & 7)) << 3)];
    }

  float m_st[2] = {-1e30f, -1e30f}, l_st[2] = {0.f, 0.f};
  f32x4 O[2][8];
  #pragma unroll
  for (int qb = 0; qb < 2; qb++)
    #pragma unroll
    for (int hb = 0; hb < 8; hb++) O[qb][hb] = f32x4{0.f, 0.f, 0.f, 0.f};

  for (int j = 0; j < 16; j++) {
    __syncthreads();
    {
      size_t kbase = ((size_t)(b * TT + j * 128)) * KHC + kh * HD;
      size_t vbase = ((size_t)((b * KVH + kh) * HD)) * TT + j * 128;
      #pragma unroll
      for (int c2 = 0; c2 < 8; c2++) {
        int flat = c2 * 256 + tid;
        int r = flat >> 4, c = flat & 15;
        int sw = (c ^ (r & 7)) << 3;
        *(uint4*)&Ks[r * 128 + sw] = *(const uint4*)&kr[kbase + (size_t)r * KHC + (c << 3)];
        *(uint4*)&Vs[r * 128 + sw] = *(const uint4*)&vT[vbase + (size_t)r * TT + (c << 3)];
      }
    }
    __syncthreads();
    f32x4 S[2][8];
    #pragma unroll
    for (int qb = 0; qb < 2; qb++)
      #pragma unroll
      for (int mb = 0; mb < 8; mb++) S[qb][mb] = f32x4{0.f, 0.f, 0.f, 0.f};
    #pragma unroll
    for (int mb = 0; mb < 8; mb++) {
      int r = mb * 16 + l16;
      #pragma unroll
      for (int ku = 0; ku < 4; ku++) {
        s16x8 kf = *(const s16x8*)&Ks[r * 128 + (((ku * 4 + q4) ^ (r & 7)) << 3)];
        S[0][mb] = __builtin_amdgcn_mfma_f32_16x16x32_bf16(kf, qf[0][ku], S[0][mb], 0, 0, 0);
        S[1][mb] = __builtin_amdgcn_mfma_f32_16x16x32_bf16(kf, qf[1][ku], S[1][mb], 0, 0, 0);
      }
    }
    s16x4 pf[2][8];
    #pragma unroll
    for (int qb = 0; qb < 2; qb++) {
      float mx = -1e30f;
      #pragma unroll
      for (int mb = 0; mb < 8; mb++)
        #pragma unroll
        for (int r = 0; r < 4; r++) mx = fmaxf(mx, S[qb][mb][r]);
      mx = fmaxf(mx, __shfl_xor(mx, 16));
      mx = fmaxf(mx, __shfl_xor(mx, 32));
      float mn = fmaxf(m_st[qb], mx);
      float alpha = __expf(m_st[qb] - mn);
      m_st[qb] = mn;
      float rs = 0.f;
      #pragma unroll
      for (int mb = 0; mb < 8; mb++)
        #pragma unroll
        for (int r = 0; r < 4; r++) {
          float p = __expf(S[qb][mb][r] - mn);
          rs += p;
          pf[qb][mb][r] = (short)f2bf(p);
        }
      rs += __shfl_xor(rs, 16);
      rs += __shfl_xor(rs, 32);
      l_st[qb] = l_st[qb] * alpha + rs;
      #pragma unroll
      for (int hb = 0; hb < 8; hb++) O[qb][hb] *= alpha;
    }
    #pragma unroll
    for (int su = 0; su < 8; su++) {
      #pragma unroll
      for (int hb = 0; hb < 8; hb++) {
        int r = hb * 16 + l16;
        int col4 = su * 4 + q4;
        s16x4 vf = *(const s16x4*)&Vs[r * 128 + (((col4 >> 1) ^ (r & 7)) << 3) + ((col4 & 1) << 2)];
        O[0][hb] = MFMA16(vf, pf[0][su], O[0][hb]);
        O[1][hb] = MFMA16(vf, pf[1][su], O[1][hb]);
      }
    }
  }
#ifdef MFMA16_ASM_FALLBACK
  asm volatile("s_nop 7\n\ts_nop 7\n\ts_nop 7" ::: "memory");
#endif
  #pragma unroll
  for (int qb = 0; qb < 2; qb++) {
    float inv = 1.f / l_st[qb];
    int t = b * TT + qt * 128 + wave * 32 + qb * 16 + l16;
    #pragma unroll
    for (int hb = 0; hb < 8; hb++) {
      ushort4 o;
      o.x = f2bf(O[qb][hb][0] * inv);
      o.y = f2bf(O[qb][hb][1] * inv);
      o.z = f2bf(O[qb][hb][2] * inv);
      o.w = f2bf(O[qb][hb][3] * inv);
      *(ushort4*)&enc[(size_t)t * NHC + n * HD + hb * 16 + q4 * 4] = o;
    }
  }
}

extern "C" void kernel_launch(void* const* d_in, const int* in_sizes, int n_in,
                              void* d_out, int out_size, void* d_ws, size_t ws_size,
                              hipStream_t stream) {
  const float* x  = (const float*)d_in[0];
  const float* Wq = (const float*)d_in[1];
  const float* Wk = (const float*)d_in[2];
  const float* Wv = (const float*)d_in[3];
  const float* Wo = (const float*)d_in[4];
  float* out = (float*)d_out;

  char* ws = (char*)d_ws;
  size_t off = 0;
  auto alloc = [&](size_t bytes) -> void* {
    void* p = ws + off;
    off += (bytes + 255) & ~(size_t)255;
    return p;
  };
  unsigned short* xb    = (unsigned short*)alloc((size_t)BT * CC * 2);
  unsigned short* wqkvt = (unsigned short*)alloc((size_t)QKVC * CC * 2);
  unsigned short* wot   = (unsigned short*)alloc((size_t)CC * NHC * 2);
  unsigned short* qkv   = (unsigned short*)alloc((size_t)BT * QKVC * 2);
  unsigned short* qrb   = (unsigned short*)alloc((size_t)BT * NHC * 2);
  unsigned short* krb   = (unsigned short*)alloc((size_t)BT * KHC * 2);
  unsigned short* vTb   = (unsigned short*)alloc((size_t)BB * KVH * HD * TT * 2);
  unsigned short* encb  = (unsigned short*)alloc((size_t)BT * NHC * 2);
  float* stab = (float*)alloc((size_t)TT * 64 * 4);
  float* ctab = (float*)alloc((size_t)TT * 64 * 4);

  dim3 tb(32, 8);
  cvt_f2b<<<(BT*CC/4 + 255)/256, 256, 0, stream>>>(x, xb, BT*CC/4);
  trans_f2b<<<dim3(NHC/32, CC/32), tb, 0, stream>>>(Wq, wqkvt, CC, NHC);
  trans_f2b<<<dim3(KHC/32, CC/32), tb, 0, stream>>>(Wk, wqkvt + (size_t)NHC*CC, CC, KHC);
  trans_f2b<<<dim3(KHC/32, CC/32), tb, 0, stream>>>(Wv, wqkvt + (size_t)(NHC+KHC)*CC, CC, KHC);
  trans_f2b<<<dim3(NHC/32, NHC/32), tb, 0, stream>>>(Wo, wot, NHC, CC);
  sincos_init<<<(TT*64 + 255)/256, 256, 0, stream>>>(stab, ctab);
  gemm_nt<1><<<dim3(QKVC/128, BT/128), 256, 0, stream>>>(xb, wqkvt, qkv, BT, QKVC, CC);
  postproc<<<BT, 256, 0, stream>>>(qkv, qrb, krb, stab, ctab);
  trans_v<<<dim3(TT/32, HD/32, BB*KVH), tb, 0, stream>>>(qkv, vTb);
  attn<<<BB * NHEAD * (TT/128), 256, 0, stream>>>(qrb, krb, vTb, encb);
  gemm_nt<0><<<dim3(CC/128, BT/128), 256, 0, stream>>>(encb, wot, out, BT, CC, NHC);
}